// Round 2
// baseline (274.127 us; speedup 1.0000x reference)
//
#include <hip/hip_runtime.h>

// RegionSelector: (64,3,512,512) fp32 -> per-batch argmax of 3x3 grid-cell-window sums -> int32 coords [64,1,2]
//
// Kernel A: partial cell sums. block = (b, c, gy, row-half): 64 rows x 512 cols, float4 loads.
//           Each 32-lane half-wave covers exactly one gx cell stripe; __shfl_down reduce,
//           each block OVERWRITES its 8 private partial slots in d_ws (no zero-init, no atomics).
// Kernel B: per-b reduce partials -> 4x4 cells -> 3x3 window sums -> first-max argmax -> int32 coords.

#define NB 64
#define NC 3
#define HW 512
#define NBLK (NB * NC * 4 * 2)   // 1536

__global__ __launch_bounds__(256) void rs_cell_sums(const float* __restrict__ in,
                                                    float* __restrict__ part) {
    // bid = ((b*3 + c)*4 + gy)*2 + half
    const int bid  = blockIdx.x;
    const int half = bid & 1;
    const int gy   = (bid >> 1) & 3;
    const int bc   = bid >> 3;        // b*3 + c
    const int tid  = threadIdx.x;
    const int col4 = tid & 127;       // float4 column index within 512-wide row
    const int rowp = tid >> 7;        // 0/1: which row of the 2-row stripe

    // base of this block's contiguous 64-row x 512-col slab
    const float4* base = (const float4*)(in + (((size_t)bc * HW) + gy * 128 + half * 64) * HW);

    float acc = 0.0f;
    #pragma unroll 8
    for (int i = 0; i < 32; ++i) {
        float4 v = base[(size_t)(i * 2 + rowp) * 128 + col4];
        acc += (v.x + v.y) + (v.z + v.w);
    }

    // reduce within each 32-lane half-wave (one half-wave == one gx stripe)
    #pragma unroll
    for (int s = 16; s > 0; s >>= 1)
        acc += __shfl_down(acc, s, 32);

    const int lane = tid & 63;
    if ((lane & 31) == 0) {
        const int w = tid >> 6;       // wave id 0..3
        const int h = lane >> 5;      // half-wave id 0/1
        // slot g = w*2 + h;  gx = (w&1)*2 + h  =>  cell gx lives at g in {gx, gx+4}
        part[bid * 8 + w * 2 + h] = acc;
    }
}

__global__ void rs_select(const float* __restrict__ part, int* __restrict__ out) {
    const int b = threadIdx.x;
    if (b >= NB) return;

    float cell[4][4];
    #pragma unroll
    for (int gy = 0; gy < 4; ++gy)
        #pragma unroll
        for (int gx = 0; gx < 4; ++gx) {
            float s = 0.0f;
            #pragma unroll
            for (int c = 0; c < NC; ++c)
                #pragma unroll
                for (int half = 0; half < 2; ++half) {
                    const int bid = ((b * NC + c) * 4 + gy) * 2 + half;
                    s += part[bid * 8 + gx] + part[bid * 8 + gx + 4];
                }
            cell[gy][gx] = s;
        }

    // 3x3 valid window sums over the 4x4 cell grid -> 2x2, flattened row-major
    float w[4];
    int k = 0;
    #pragma unroll
    for (int r = 0; r < 2; ++r)
        #pragma unroll
        for (int c = 0; c < 2; ++c) {
            float s = 0.0f;
            #pragma unroll
            for (int dy = 0; dy < 3; ++dy)
                #pragma unroll
                for (int dx = 0; dx < 3; ++dx)
                    s += cell[r + dy][c + dx];
            w[k++] = s;
        }

    // first-max argmax (lax.top_k tie-break: lowest index wins)
    int best = 0;
    #pragma unroll
    for (int i = 1; i < 4; ++i)
        if (w[i] > w[best]) best = i;

    out[b * 2 + 0] = best >> 1;   // row = idx // 2
    out[b * 2 + 1] = best & 1;    // col = idx % 2
}

extern "C" void kernel_launch(void* const* d_in, const int* in_sizes, int n_in,
                              void* d_out, int out_size, void* d_ws, size_t ws_size,
                              hipStream_t stream) {
    const float* in = (const float*)d_in[0];
    float* part = (float*)d_ws;        // needs NBLK*8*4 = 48 KB
    int* out = (int*)d_out;            // int32 coords, out_size = 128

    rs_cell_sums<<<NBLK, 256, 0, stream>>>(in, part);
    rs_select<<<1, 64, 0, stream>>>(part, out);
}